// Round 1
// baseline (10156.017 us; speedup 1.0000x reference)
//
#include <hip/hip_runtime.h>
#include <math.h>

// ---------------- elementwise / degree kernels ----------------

__global__ __launch_bounds__(256) void k_set1(float* __restrict__ p, int n) {
    int i = blockIdx.x * 256 + threadIdx.x;
    if (i < n) p[i] = 1.0f;   // self-loop contributes 1 to every node's degree
}

__global__ __launch_bounds__(256) void k_count(const int* __restrict__ dst, float* __restrict__ deg, int E) {
    int e = blockIdx.x * 256 + threadIdx.x;
    if (e < E) unsafeAtomicAdd(&deg[dst[e]], 1.0f);
}

__global__ __launch_bounds__(256) void k_dinv(const float* __restrict__ deg, float* __restrict__ dinv, int n) {
    int i = blockIdx.x * 256 + threadIdx.x;
    if (i < n) dinv[i] = rsqrtf(fmaxf(deg[i], 1e-12f));
}

__global__ __launch_bounds__(256) void k_norm(const int* __restrict__ src, const int* __restrict__ dst,
                                              const float* __restrict__ dinv, float* __restrict__ nrm, int E) {
    int e = blockIdx.x * 256 + threadIdx.x;
    if (e < E) nrm[e] = dinv[src[e]] * dinv[dst[e]];
}

// ---------------- GEMM1: C = relu(A[M,256] @ B[256,256] + bias) ----------------
// 64x64 tile, 256 threads, 4x4 micro-tile per thread.

__global__ __launch_bounds__(256) void k_gemm1(const float* __restrict__ A, const float* __restrict__ B,
                                               const float* __restrict__ bias, float* __restrict__ C, int M) {
    __shared__ float As[16][68];   // [k][m], padded (68 floats = 17*16B keeps float4 alignment)
    __shared__ float Bs[16][64];   // [k][n]
    const int bm = blockIdx.x * 64;
    const int bn = blockIdx.y * 64;
    const int t  = threadIdx.x;
    const int tx = t & 15, ty = t >> 4;
    const int lr = t >> 2;          // 0..63: A row within tile
    const int lk = (t & 3) * 4;     // k offset for A load
    const int bkr = t >> 4;         // 0..15: B k-row
    const int bc  = (t & 15) * 4;   // B col offset

    float acc[4][4] = {{0.f}};
    for (int k0 = 0; k0 < 256; k0 += 16) {
        float4 av = make_float4(0.f, 0.f, 0.f, 0.f);
        int row = bm + lr;
        if (row < M) av = *(const float4*)&A[(size_t)row * 256 + k0 + lk];
        float4 bv = *(const float4*)&B[(size_t)(k0 + bkr) * 256 + bn + bc];
        __syncthreads();
        As[lk + 0][lr] = av.x; As[lk + 1][lr] = av.y; As[lk + 2][lr] = av.z; As[lk + 3][lr] = av.w;
        *(float4*)&Bs[bkr][bc] = bv;
        __syncthreads();
#pragma unroll
        for (int kk = 0; kk < 16; ++kk) {
            float4 a = *(const float4*)&As[kk][ty * 4];
            float4 b = *(const float4*)&Bs[kk][tx * 4];
            float avv[4] = {a.x, a.y, a.z, a.w};
            float bvv[4] = {b.x, b.y, b.z, b.w};
#pragma unroll
            for (int i = 0; i < 4; ++i)
#pragma unroll
                for (int j = 0; j < 4; ++j) acc[i][j] += avv[i] * bvv[j];
        }
    }
    int n = bn + tx * 4;
    float4 bb = *(const float4*)&bias[n];
#pragma unroll
    for (int i = 0; i < 4; ++i) {
        int m = bm + ty * 4 + i;
        if (m < M) {
            float4 o;
            o.x = fmaxf(acc[i][0] + bb.x, 0.f);
            o.y = fmaxf(acc[i][1] + bb.y, 0.f);
            o.z = fmaxf(acc[i][2] + bb.z, 0.f);
            o.w = fmaxf(acc[i][3] + bb.w, 0.f);
            *(float4*)&C[(size_t)m * 256 + n] = o;
        }
    }
}

// ---------------- GEMM2: C = A[M,256] @ B[256,48] + bias ----------------
// 64-row tile; whole W2 (48KB) staged in LDS; 4 rows x 3 cols per thread.

__global__ __launch_bounds__(256) void k_gemm2(const float* __restrict__ A, const float* __restrict__ B,
                                               const float* __restrict__ bias, float* __restrict__ C, int M) {
    __shared__ float As[16][68];
    __shared__ float Ws[256 * 48];
    const int t = threadIdx.x;
    // stage W2: 12288 floats = 3072 float4, 12 per thread, coalesced
#pragma unroll
    for (int i = 0; i < 12; ++i) {
        int idx = t + 256 * i;
        *(float4*)&Ws[idx * 4] = *(const float4*)&B[(size_t)idx * 4];
    }
    const int bm = blockIdx.x * 64;
    const int tx = t & 15, ty = t >> 4;
    const int lr = t >> 2;
    const int lk = (t & 3) * 4;
    float acc[4][3] = {{0.f}};
    for (int k0 = 0; k0 < 256; k0 += 16) {
        float4 av = make_float4(0.f, 0.f, 0.f, 0.f);
        int row = bm + lr;
        if (row < M) av = *(const float4*)&A[(size_t)row * 256 + k0 + lk];
        __syncthreads();     // also covers Ws stores on first iteration
        As[lk + 0][lr] = av.x; As[lk + 1][lr] = av.y; As[lk + 2][lr] = av.z; As[lk + 3][lr] = av.w;
        __syncthreads();
#pragma unroll
        for (int kk = 0; kk < 16; ++kk) {
            float4 a = *(const float4*)&As[kk][ty * 4];
            float avv[4] = {a.x, a.y, a.z, a.w};
#pragma unroll
            for (int j = 0; j < 3; ++j) {
                float b = Ws[(k0 + kk) * 48 + tx * 3 + j];
#pragma unroll
                for (int i = 0; i < 4; ++i) acc[i][j] += avv[i] * b;
            }
        }
    }
#pragma unroll
    for (int i = 0; i < 4; ++i) {
        int m = bm + ty * 4 + i;
        if (m < M) {
#pragma unroll
            for (int j = 0; j < 3; ++j) {
                int n = tx * 3 + j;
                C[(size_t)m * 48 + n] = acc[i][j] + bias[n];
            }
        }
    }
}

// ---------------- propagation ----------------
// seed: hidden (init or +=) gamma*cur ; nxt = dinv[node]^2 * cur   (self-loop term)
__global__ __launch_bounds__(256) void k_seed(const float4* __restrict__ cur, float4* __restrict__ nxt,
                                              float4* __restrict__ hidden, const float* __restrict__ temp,
                                              int gi, int init, const float* __restrict__ dinv, int n4) {
    int t = blockIdx.x * 256 + threadIdx.x;
    if (t >= n4) return;
    float g = temp[gi];
    int node = t / 12;              // 48 floats = 12 float4 per row
    float di = dinv[node];
    float w = di * di;
    float4 v = cur[t];
    float4 hv;
    if (init) {
        hv = make_float4(g * v.x, g * v.y, g * v.z, g * v.w);
    } else {
        hv = hidden[t];
        hv.x += g * v.x; hv.y += g * v.y; hv.z += g * v.z; hv.w += g * v.w;
    }
    hidden[t] = hv;
    nxt[t] = make_float4(w * v.x, w * v.y, w * v.z, w * v.w);
}

// edge scatter: nxt[dst] += norm_e * cur[src]; 12 threads per edge (float4 each)
__global__ __launch_bounds__(192) void k_scatter(const int* __restrict__ src, const int* __restrict__ dst,
                                                 const float* __restrict__ nrm, const float* __restrict__ cur,
                                                 float* __restrict__ nxt, int E) {
    int t = blockIdx.x * 192 + threadIdx.x;
    int e = t / 12;
    int g = t % 12;
    if (e >= E) return;
    int s = src[e], d = dst[e];
    float w = nrm[e];
    float4 v = ((const float4*)(cur + (size_t)s * 48))[g];
    float* o = nxt + (size_t)d * 48 + g * 4;
    unsafeAtomicAdd(o + 0, w * v.x);
    unsafeAtomicAdd(o + 1, w * v.y);
    unsafeAtomicAdd(o + 2, w * v.z);
    unsafeAtomicAdd(o + 3, w * v.w);
}

// ---------------- final: out = log_softmax(hidden + temp[10]*cur) ----------------
__global__ __launch_bounds__(256) void k_final(const float* __restrict__ hidden, const float* __restrict__ cur,
                                               const float* __restrict__ temp, float* __restrict__ out, int N) {
    int w = (blockIdx.x * 256 + threadIdx.x) >> 6;   // one wave per row
    int lane = threadIdx.x & 63;
    if (w >= N) return;
    float g = temp[10];
    float val = 0.f, m = -INFINITY;
    if (lane < 48) {
        val = hidden[(size_t)w * 48 + lane] + g * cur[(size_t)w * 48 + lane];
        m = val;
    }
#pragma unroll
    for (int off = 32; off; off >>= 1) m = fmaxf(m, __shfl_xor(m, off));
    float ex = (lane < 48) ? __expf(val - m) : 0.f;
    float s = ex;
#pragma unroll
    for (int off = 32; off; off >>= 1) s += __shfl_xor(s, off);
    if (lane < 48) out[(size_t)w * 48 + lane] = val - m - __logf(s);
}

// ---------------- launch ----------------

extern "C" void kernel_launch(void* const* d_in, const int* in_sizes, int n_in,
                              void* d_out, int out_size, void* d_ws, size_t ws_size,
                              hipStream_t stream) {
    const float* x    = (const float*)d_in[0];
    const int*   ei   = (const int*)d_in[1];
    const float* W1   = (const float*)d_in[2];
    const float* b1   = (const float*)d_in[3];
    const float* W2   = (const float*)d_in[4];
    const float* b2   = (const float*)d_in[5];
    const float* temp = (const float*)d_in[6];
    float* out = (float*)d_out;

    const int N = in_sizes[0] / 256;
    const int E = in_sizes[1] / 2;
    const int* src = ei;
    const int* dst = ei + E;

    // workspace layout (floats), all float4-aligned
    float* f = (float*)d_ws;
    size_t NP = (size_t)((N + 63) & ~63);
    size_t EP = (size_t)((E + 15) & ~15);
    float* deg    = f;
    float* dinv   = deg + NP;
    float* nrm    = dinv + NP;
    float* h1     = nrm + EP;                 // N x 256
    float* h      = h1 + (size_t)N * 256;     // N x 48
    float* bufA   = h + (size_t)N * 48;
    float* bufB   = bufA + (size_t)N * 48;
    float* hidden = bufB + (size_t)N * 48;

    // degree / norm
    k_set1 <<<(N + 255) / 256, 256, 0, stream>>>(deg, N);
    k_count<<<(E + 255) / 256, 256, 0, stream>>>(dst, deg, E);
    k_dinv <<<(N + 255) / 256, 256, 0, stream>>>(deg, dinv, N);
    k_norm <<<(E + 255) / 256, 256, 0, stream>>>(src, dst, dinv, nrm, E);

    // MLP head
    dim3 g1((N + 63) / 64, 4);
    k_gemm1<<<g1, 256, 0, stream>>>(x, W1, b1, h1, N);
    k_gemm2<<<(N + 63) / 64, 256, 0, stream>>>(h1, W2, b2, h, N);

    // K-hop propagation
    const int n4 = N * 12;
    const float* cur = h;
    float* nxt = bufA;
    for (int k = 0; k < 10; ++k) {
        k_seed<<<(n4 + 255) / 256, 256, 0, stream>>>((const float4*)cur, (float4*)nxt, (float4*)hidden,
                                                     temp, k, (k == 0) ? 1 : 0, dinv, n4);
        long tt = (long)E * 12;
        k_scatter<<<(int)((tt + 191) / 192), 192, 0, stream>>>(src, dst, nrm, cur, nxt, E);
        cur = nxt;
        nxt = (nxt == bufA) ? bufB : bufA;
    }

    k_final<<<(N / 4) + 1, 256, 0, stream>>>(hidden, cur, temp, out, N);
}

// Round 2
// 1136.161 us; speedup vs baseline: 8.9389x; 8.9389x over previous
//
#include <hip/hip_runtime.h>
#include <math.h>

// ---------------- zero / degree / norm ----------------

__global__ __launch_bounds__(256) void k_zero(int* __restrict__ p, int n) {
    int i = blockIdx.x * 256 + threadIdx.x;
    if (i < n) p[i] = 0;
}

__global__ __launch_bounds__(256) void k_count(const int* __restrict__ dst, int* __restrict__ cnt, int E) {
    int e = blockIdx.x * 256 + threadIdx.x;
    if (e < E) atomicAdd(&cnt[dst[e]], 1);
}

__global__ __launch_bounds__(256) void k_dinv(const int* __restrict__ cnt, float* __restrict__ dinv, int n) {
    int i = blockIdx.x * 256 + threadIdx.x;
    if (i < n) dinv[i] = rsqrtf((float)cnt[i] + 1.0f);   // +1 self-loop; >=1 so no clamp needed
}

// ---------------- CSR build: scan + fill ----------------
// N = 50000 -> 196 scan blocks (must be <= 256 for k_scan2's single block)

__global__ __launch_bounds__(256) void k_scan1(const int* __restrict__ cnt, int* __restrict__ rowptr,
                                               int* __restrict__ blk, int N) {
    __shared__ int s[256];
    int t = threadIdx.x, i = blockIdx.x * 256 + t;
    int v = (i < N) ? cnt[i] : 0;
    s[t] = v; __syncthreads();
#pragma unroll
    for (int off = 1; off < 256; off <<= 1) {
        int x = (t >= off) ? s[t - off] : 0; __syncthreads();
        s[t] += x; __syncthreads();
    }
    if (i < N) rowptr[i] = s[t] - v;          // exclusive within block
    if (t == 255) blk[blockIdx.x] = s[255];   // block total
}

__global__ __launch_bounds__(256) void k_scan2(int* __restrict__ blk, int nb) {
    __shared__ int s[256];
    int t = threadIdx.x;
    int v = (t < nb) ? blk[t] : 0;
    s[t] = v; __syncthreads();
#pragma unroll
    for (int off = 1; off < 256; off <<= 1) {
        int x = (t >= off) ? s[t - off] : 0; __syncthreads();
        s[t] += x; __syncthreads();
    }
    if (t < nb) blk[t] = s[t] - v;            // exclusive block offsets
}

__global__ __launch_bounds__(256) void k_scan3(int* __restrict__ rowptr, int* __restrict__ cursor,
                                               const int* __restrict__ blk, int N) {
    int i = blockIdx.x * 256 + threadIdx.x;
    if (i < N) {
        int r = rowptr[i] + blk[blockIdx.x];
        rowptr[i] = r;
        cursor[i] = r;                         // fill cursor starts at row start
    }
}

__global__ __launch_bounds__(256) void k_fill(const int* __restrict__ src, const int* __restrict__ dst,
                                              const float* __restrict__ dinv, int* __restrict__ cursor,
                                              int* __restrict__ csr_src, float* __restrict__ csr_w, int E) {
    int e = blockIdx.x * 256 + threadIdx.x;
    if (e >= E) return;
    int s = src[e], d = dst[e];
    int pos = atomicAdd(&cursor[d], 1);
    csr_src[pos] = s;
    csr_w[pos] = dinv[s] * dinv[d];
}
// after k_fill, cursor[n] == rowptr[n] + cnt[n] == row end

// ---------------- GEMM1: C = relu(A[M,256] @ B[256,256] + bias) ----------------

__global__ __launch_bounds__(256) void k_gemm1(const float* __restrict__ A, const float* __restrict__ B,
                                               const float* __restrict__ bias, float* __restrict__ C, int M) {
    __shared__ float As[16][68];
    __shared__ float Bs[16][64];
    const int bm = blockIdx.x * 64;
    const int bn = blockIdx.y * 64;
    const int t  = threadIdx.x;
    const int tx = t & 15, ty = t >> 4;
    const int lr = t >> 2;
    const int lk = (t & 3) * 4;
    const int bkr = t >> 4;
    const int bc  = (t & 15) * 4;

    float acc[4][4] = {{0.f}};
    for (int k0 = 0; k0 < 256; k0 += 16) {
        float4 av = make_float4(0.f, 0.f, 0.f, 0.f);
        int row = bm + lr;
        if (row < M) av = *(const float4*)&A[(size_t)row * 256 + k0 + lk];
        float4 bv = *(const float4*)&B[(size_t)(k0 + bkr) * 256 + bn + bc];
        __syncthreads();
        As[lk + 0][lr] = av.x; As[lk + 1][lr] = av.y; As[lk + 2][lr] = av.z; As[lk + 3][lr] = av.w;
        *(float4*)&Bs[bkr][bc] = bv;
        __syncthreads();
#pragma unroll
        for (int kk = 0; kk < 16; ++kk) {
            float4 a = *(const float4*)&As[kk][ty * 4];
            float4 b = *(const float4*)&Bs[kk][tx * 4];
            float avv[4] = {a.x, a.y, a.z, a.w};
            float bvv[4] = {b.x, b.y, b.z, b.w};
#pragma unroll
            for (int i = 0; i < 4; ++i)
#pragma unroll
                for (int j = 0; j < 4; ++j) acc[i][j] += avv[i] * bvv[j];
        }
    }
    int n = bn + tx * 4;
    float4 bb = *(const float4*)&bias[n];
#pragma unroll
    for (int i = 0; i < 4; ++i) {
        int m = bm + ty * 4 + i;
        if (m < M) {
            float4 o;
            o.x = fmaxf(acc[i][0] + bb.x, 0.f);
            o.y = fmaxf(acc[i][1] + bb.y, 0.f);
            o.z = fmaxf(acc[i][2] + bb.z, 0.f);
            o.w = fmaxf(acc[i][3] + bb.w, 0.f);
            *(float4*)&C[(size_t)m * 256 + n] = o;
        }
    }
}

// ---------------- GEMM2: C = A[M,256] @ B[256,48] + bias ----------------

__global__ __launch_bounds__(256) void k_gemm2(const float* __restrict__ A, const float* __restrict__ B,
                                               const float* __restrict__ bias, float* __restrict__ C, int M) {
    __shared__ float As[16][68];
    __shared__ float Ws[256 * 48];
    const int t = threadIdx.x;
#pragma unroll
    for (int i = 0; i < 12; ++i) {
        int idx = t + 256 * i;
        *(float4*)&Ws[idx * 4] = *(const float4*)&B[(size_t)idx * 4];
    }
    const int bm = blockIdx.x * 64;
    const int tx = t & 15, ty = t >> 4;
    const int lr = t >> 2;
    const int lk = (t & 3) * 4;
    float acc[4][3] = {{0.f}};
    for (int k0 = 0; k0 < 256; k0 += 16) {
        float4 av = make_float4(0.f, 0.f, 0.f, 0.f);
        int row = bm + lr;
        if (row < M) av = *(const float4*)&A[(size_t)row * 256 + k0 + lk];
        __syncthreads();
        As[lk + 0][lr] = av.x; As[lk + 1][lr] = av.y; As[lk + 2][lr] = av.z; As[lk + 3][lr] = av.w;
        __syncthreads();
#pragma unroll
        for (int kk = 0; kk < 16; ++kk) {
            float4 a = *(const float4*)&As[kk][ty * 4];
            float avv[4] = {a.x, a.y, a.z, a.w};
#pragma unroll
            for (int j = 0; j < 3; ++j) {
                float b = Ws[(k0 + kk) * 48 + tx * 3 + j];
#pragma unroll
                for (int i = 0; i < 4; ++i) acc[i][j] += avv[i] * b;
            }
        }
    }
#pragma unroll
    for (int i = 0; i < 4; ++i) {
        int m = bm + ty * 4 + i;
        if (m < M) {
#pragma unroll
            for (int j = 0; j < 3; ++j) {
                int n = tx * 3 + j;
                C[(size_t)m * 48 + n] = acc[i][j] + bias[n];
            }
        }
    }
}

// ---------------- fused hop: hidden (init/+=) g*cur ; nxt = Ahat * cur (gather) ----------------
// 12 threads per node, one float4 lane each. csr reads broadcast across the team.

__global__ __launch_bounds__(256) void k_hop(const float4* __restrict__ cur, float4* __restrict__ nxt,
                                             float4* __restrict__ hidden,
                                             const int* __restrict__ rowptr, const int* __restrict__ rowend,
                                             const int* __restrict__ csr_src, const float* __restrict__ csr_w,
                                             const float* __restrict__ dinv, const float* __restrict__ temp,
                                             int gi, int init, int N) {
    int t = blockIdx.x * 256 + threadIdx.x;
    int n = t / 12;
    if (n >= N) return;
    int c = t - n * 12;
    float4 cv = cur[t];
    float g = temp[gi];
    float4 hv;
    if (init) {
        hv = make_float4(g * cv.x, g * cv.y, g * cv.z, g * cv.w);
    } else {
        hv = hidden[t];
        hv.x += g * cv.x; hv.y += g * cv.y; hv.z += g * cv.z; hv.w += g * cv.w;
    }
    hidden[t] = hv;

    float di = dinv[n];
    float w0 = di * di;
    float4 acc = make_float4(w0 * cv.x, w0 * cv.y, w0 * cv.z, w0 * cv.w);
    int e = rowptr[n], e1 = rowend[n];
    for (; e < e1; ++e) {
        int s = csr_src[e];
        float w = csr_w[e];
        float4 v = cur[(size_t)s * 12 + c];
        acc.x += w * v.x; acc.y += w * v.y; acc.z += w * v.z; acc.w += w * v.w;
    }
    nxt[t] = acc;
}

// ---------------- final: out = log_softmax(hidden + temp[10]*cur) ----------------

__global__ __launch_bounds__(256) void k_final(const float* __restrict__ hidden, const float* __restrict__ cur,
                                               const float* __restrict__ temp, float* __restrict__ out, int N) {
    int w = (blockIdx.x * 256 + threadIdx.x) >> 6;
    int lane = threadIdx.x & 63;
    if (w >= N) return;
    float g = temp[10];
    float val = 0.f, m = -INFINITY;
    if (lane < 48) {
        val = hidden[(size_t)w * 48 + lane] + g * cur[(size_t)w * 48 + lane];
        m = val;
    }
#pragma unroll
    for (int off = 32; off; off >>= 1) m = fmaxf(m, __shfl_xor(m, off));
    float ex = (lane < 48) ? __expf(val - m) : 0.f;
    float s = ex;
#pragma unroll
    for (int off = 32; off; off >>= 1) s += __shfl_xor(s, off);
    if (lane < 48) out[(size_t)w * 48 + lane] = val - m - __logf(s);
}

// ---------------- launch ----------------

extern "C" void kernel_launch(void* const* d_in, const int* in_sizes, int n_in,
                              void* d_out, int out_size, void* d_ws, size_t ws_size,
                              hipStream_t stream) {
    const float* x    = (const float*)d_in[0];
    const int*   ei   = (const int*)d_in[1];
    const float* W1   = (const float*)d_in[2];
    const float* b1   = (const float*)d_in[3];
    const float* W2   = (const float*)d_in[4];
    const float* b2   = (const float*)d_in[5];
    const float* temp = (const float*)d_in[6];
    float* out = (float*)d_out;

    const int N = in_sizes[0] / 256;
    const int E = in_sizes[1] / 2;
    const int* src = ei;
    const int* dst = ei + E;

    // workspace layout (4-byte units, all float4-aligned)
    char* w8 = (char*)d_ws;
    size_t NP = (size_t)((N + 63) & ~63);
    int*   cnt     = (int*)w8;                       // N
    int*   rowptr  = cnt + NP;                       // N
    int*   cursor  = rowptr + NP;                    // N
    int*   blk     = cursor + NP;                    // 256
    float* dinv    = (float*)(blk + 256);            // N
    int*   csr_src = (int*)(dinv + NP);              // E
    float* csr_w   = (float*)(csr_src + ((E + 15) & ~15)); // E
    float* h       = csr_w + ((E + 15) & ~15);       // N*48
    float* bufB    = h + (size_t)N * 48;             // N*48
    float* hidden  = bufB + (size_t)N * 48;          // N*48
    float* h1      = hidden + (size_t)N * 48;        // N*256 (dead after gemm2)
    float* bufA    = h1;                             // aliases h1 (9.6MB <= 12.8MB)

    const int nb = (N + 255) / 256;                  // 196 <= 256 (k_scan2 single-block limit)

    // CSR build
    k_zero <<<(N + 255) / 256, 256, 0, stream>>>(cnt, N);
    k_count<<<(E + 255) / 256, 256, 0, stream>>>(dst, cnt, E);
    k_dinv <<<(N + 255) / 256, 256, 0, stream>>>(cnt, dinv, N);
    k_scan1<<<nb, 256, 0, stream>>>(cnt, rowptr, blk, N);
    k_scan2<<<1, 256, 0, stream>>>(blk, nb);
    k_scan3<<<nb, 256, 0, stream>>>(rowptr, cursor, blk, N);
    k_fill <<<(E + 255) / 256, 256, 0, stream>>>(src, dst, dinv, cursor, csr_src, csr_w, E);

    // MLP head
    dim3 g1((N + 63) / 64, 4);
    k_gemm1<<<g1, 256, 0, stream>>>(x, W1, b1, h1, N);
    k_gemm2<<<(N + 63) / 64, 256, 0, stream>>>(h1, W2, b2, h, N);

    // K-hop propagation (gather form, fused hidden update)
    const int n4 = N * 12;
    const float* cur = h;
    float* nxt = bufA;
    for (int k = 0; k < 10; ++k) {
        k_hop<<<(n4 + 255) / 256, 256, 0, stream>>>((const float4*)cur, (float4*)nxt, (float4*)hidden,
                                                    rowptr, cursor, csr_src, csr_w, dinv, temp,
                                                    k, (k == 0) ? 1 : 0, N);
        cur = nxt;
        nxt = (nxt == bufA) ? bufB : bufA;
    }

    k_final<<<(N / 4) + 1, 256, 0, stream>>>(hidden, cur, temp, out, N);
}

// Round 3
// 926.456 us; speedup vs baseline: 10.9622x; 1.2264x over previous
//
#include <hip/hip_runtime.h>
#include <math.h>

// ---------------- zero / degree / norm ----------------

__global__ __launch_bounds__(256) void k_zero(int* __restrict__ p, int n) {
    int i = blockIdx.x * 256 + threadIdx.x;
    if (i < n) p[i] = 0;
}

__global__ __launch_bounds__(256) void k_count(const int* __restrict__ dst, int* __restrict__ cnt, int E) {
    int e = blockIdx.x * 256 + threadIdx.x;
    if (e < E) atomicAdd(&cnt[dst[e]], 1);
}

// dinv = deg^-1/2 ; dinv2 = deg^-1 ; sdeg = deg^1/2   (deg includes +1 self-loop)
__global__ __launch_bounds__(256) void k_dinv(const int* __restrict__ cnt, float* __restrict__ dinv,
                                              float* __restrict__ dinv2, float* __restrict__ sdeg, int n) {
    int i = blockIdx.x * 256 + threadIdx.x;
    if (i < n) {
        float d = (float)cnt[i] + 1.0f;
        float r = rsqrtf(d);
        dinv[i] = r;
        dinv2[i] = r * r;
        sdeg[i] = d * r;   // sqrt(d)
    }
}

// ---------------- CSR build: scan + fill ----------------

__global__ __launch_bounds__(256) void k_scan1(const int* __restrict__ cnt, int* __restrict__ rowptr,
                                               int* __restrict__ blk, int N) {
    __shared__ int s[256];
    int t = threadIdx.x, i = blockIdx.x * 256 + t;
    int v = (i < N) ? cnt[i] : 0;
    s[t] = v; __syncthreads();
#pragma unroll
    for (int off = 1; off < 256; off <<= 1) {
        int x = (t >= off) ? s[t - off] : 0; __syncthreads();
        s[t] += x; __syncthreads();
    }
    if (i < N) rowptr[i] = s[t] - v;
    if (t == 255) blk[blockIdx.x] = s[255];
}

__global__ __launch_bounds__(256) void k_scan2(int* __restrict__ blk, int nb) {
    __shared__ int s[256];
    int t = threadIdx.x;
    int v = (t < nb) ? blk[t] : 0;
    s[t] = v; __syncthreads();
#pragma unroll
    for (int off = 1; off < 256; off <<= 1) {
        int x = (t >= off) ? s[t - off] : 0; __syncthreads();
        s[t] += x; __syncthreads();
    }
    if (t < nb) blk[t] = s[t] - v;
}

__global__ __launch_bounds__(256) void k_scan3(int* __restrict__ rowptr, int* __restrict__ cursor,
                                               const int* __restrict__ blk, int N) {
    int i = blockIdx.x * 256 + threadIdx.x;
    if (i < N) {
        int r = rowptr[i] + blk[blockIdx.x];
        rowptr[i] = r;
        cursor[i] = r;
    }
}

// one 4B scattered store per edge (src only — weights folded into u-state algebra)
__global__ __launch_bounds__(256) void k_fill(const int* __restrict__ src, const int* __restrict__ dst,
                                              int* __restrict__ cursor, int* __restrict__ csr_src, int E) {
    int e = blockIdx.x * 256 + threadIdx.x;
    if (e >= E) return;
    int s = src[e], d = dst[e];
    int pos = atomicAdd(&cursor[d], 1);
    csr_src[pos] = s;
}

// ---------------- GEMM1: C = relu(A[M,256] @ B[256,256] + bias) ----------------

__global__ __launch_bounds__(256) void k_gemm1(const float* __restrict__ A, const float* __restrict__ B,
                                               const float* __restrict__ bias, float* __restrict__ C, int M) {
    __shared__ float As[16][68];
    __shared__ float Bs[16][64];
    const int bm = blockIdx.x * 64;
    const int bn = blockIdx.y * 64;
    const int t  = threadIdx.x;
    const int tx = t & 15, ty = t >> 4;
    const int lr = t >> 2;
    const int lk = (t & 3) * 4;
    const int bkr = t >> 4;
    const int bc  = (t & 15) * 4;

    float acc[4][4] = {{0.f}};
    for (int k0 = 0; k0 < 256; k0 += 16) {
        float4 av = make_float4(0.f, 0.f, 0.f, 0.f);
        int row = bm + lr;
        if (row < M) av = *(const float4*)&A[(size_t)row * 256 + k0 + lk];
        float4 bv = *(const float4*)&B[(size_t)(k0 + bkr) * 256 + bn + bc];
        __syncthreads();
        As[lk + 0][lr] = av.x; As[lk + 1][lr] = av.y; As[lk + 2][lr] = av.z; As[lk + 3][lr] = av.w;
        *(float4*)&Bs[bkr][bc] = bv;
        __syncthreads();
#pragma unroll
        for (int kk = 0; kk < 16; ++kk) {
            float4 a = *(const float4*)&As[kk][ty * 4];
            float4 b = *(const float4*)&Bs[kk][tx * 4];
            float avv[4] = {a.x, a.y, a.z, a.w};
            float bvv[4] = {b.x, b.y, b.z, b.w};
#pragma unroll
            for (int i = 0; i < 4; ++i)
#pragma unroll
                for (int j = 0; j < 4; ++j) acc[i][j] += avv[i] * bvv[j];
        }
    }
    int n = bn + tx * 4;
    float4 bb = *(const float4*)&bias[n];
#pragma unroll
    for (int i = 0; i < 4; ++i) {
        int m = bm + ty * 4 + i;
        if (m < M) {
            float4 o;
            o.x = fmaxf(acc[i][0] + bb.x, 0.f);
            o.y = fmaxf(acc[i][1] + bb.y, 0.f);
            o.z = fmaxf(acc[i][2] + bb.z, 0.f);
            o.w = fmaxf(acc[i][3] + bb.w, 0.f);
            *(float4*)&C[(size_t)m * 256 + n] = o;
        }
    }
}

// ---------------- GEMM2: u0 = (A[M,256] @ B[256,48] + bias) * dinv[m] ----------------

__global__ __launch_bounds__(256) void k_gemm2(const float* __restrict__ A, const float* __restrict__ B,
                                               const float* __restrict__ bias, const float* __restrict__ dinv,
                                               float* __restrict__ C, int M) {
    __shared__ float As[16][68];
    __shared__ float Ws[256 * 48];
    const int t = threadIdx.x;
#pragma unroll
    for (int i = 0; i < 12; ++i) {
        int idx = t + 256 * i;
        *(float4*)&Ws[idx * 4] = *(const float4*)&B[(size_t)idx * 4];
    }
    const int bm = blockIdx.x * 64;
    const int tx = t & 15, ty = t >> 4;
    const int lr = t >> 2;
    const int lk = (t & 3) * 4;
    float acc[4][3] = {{0.f}};
    for (int k0 = 0; k0 < 256; k0 += 16) {
        float4 av = make_float4(0.f, 0.f, 0.f, 0.f);
        int row = bm + lr;
        if (row < M) av = *(const float4*)&A[(size_t)row * 256 + k0 + lk];
        __syncthreads();
        As[lk + 0][lr] = av.x; As[lk + 1][lr] = av.y; As[lk + 2][lr] = av.z; As[lk + 3][lr] = av.w;
        __syncthreads();
#pragma unroll
        for (int kk = 0; kk < 16; ++kk) {
            float4 a = *(const float4*)&As[kk][ty * 4];
            float avv[4] = {a.x, a.y, a.z, a.w};
#pragma unroll
            for (int j = 0; j < 3; ++j) {
                float b = Ws[(k0 + kk) * 48 + tx * 3 + j];
#pragma unroll
                for (int i = 0; i < 4; ++i) acc[i][j] += avv[i] * b;
            }
        }
    }
#pragma unroll
    for (int i = 0; i < 4; ++i) {
        int m = bm + ty * 4 + i;
        if (m < M) {
            float di = dinv[m];
#pragma unroll
            for (int j = 0; j < 3; ++j) {
                int n = tx * 3 + j;
                C[(size_t)m * 48 + n] = (acc[i][j] + bias[n]) * di;
            }
        }
    }
}

// ---------------- fused hop on u-state ----------------
// hidden (init/+=) g*sdeg[n]*u ; u_next[n] = dinv2[n]*(u[n] + sum_in u[s])
// 12 threads per node, one float4 lane each; edge loop unrolled x4 for ILP.

__global__ __launch_bounds__(256) void k_hop(const float4* __restrict__ u, float4* __restrict__ unxt,
                                             float4* __restrict__ hidden,
                                             const int* __restrict__ rowptr, const int* __restrict__ rowend,
                                             const int* __restrict__ csr_src,
                                             const float* __restrict__ dinv2, const float* __restrict__ sdeg,
                                             const float* __restrict__ temp,
                                             int gi, int init, int N) {
    int t = blockIdx.x * 256 + threadIdx.x;
    int n = t / 12;
    if (n >= N) return;
    int c = t - n * 12;
    float4 uv = u[t];
    float gs = temp[gi] * sdeg[n];
    float4 hv;
    if (init) {
        hv = make_float4(gs * uv.x, gs * uv.y, gs * uv.z, gs * uv.w);
    } else {
        hv = hidden[t];
        hv.x += gs * uv.x; hv.y += gs * uv.y; hv.z += gs * uv.z; hv.w += gs * uv.w;
    }
    hidden[t] = hv;

    float4 acc = uv;                      // self-loop term
    int e = rowptr[n], e1 = rowend[n];
    for (; e + 3 < e1; e += 4) {
        int s0 = csr_src[e + 0];
        int s1 = csr_src[e + 1];
        int s2 = csr_src[e + 2];
        int s3 = csr_src[e + 3];
        float4 v0 = u[(size_t)s0 * 12 + c];
        float4 v1 = u[(size_t)s1 * 12 + c];
        float4 v2 = u[(size_t)s2 * 12 + c];
        float4 v3 = u[(size_t)s3 * 12 + c];
        acc.x += v0.x + v1.x + v2.x + v3.x;
        acc.y += v0.y + v1.y + v2.y + v3.y;
        acc.z += v0.z + v1.z + v2.z + v3.z;
        acc.w += v0.w + v1.w + v2.w + v3.w;
    }
    for (; e < e1; ++e) {
        int s = csr_src[e];
        float4 v = u[(size_t)s * 12 + c];
        acc.x += v.x; acc.y += v.y; acc.z += v.z; acc.w += v.w;
    }
    float w2 = dinv2[n];
    unxt[t] = make_float4(w2 * acc.x, w2 * acc.y, w2 * acc.z, w2 * acc.w);
}

// ---------------- final: out = log_softmax(hidden + temp[10]*sdeg*u) ----------------

__global__ __launch_bounds__(256) void k_final(const float* __restrict__ hidden, const float* __restrict__ u,
                                               const float* __restrict__ sdeg, const float* __restrict__ temp,
                                               float* __restrict__ out, int N) {
    int w = (blockIdx.x * 256 + threadIdx.x) >> 6;
    int lane = threadIdx.x & 63;
    if (w >= N) return;
    float g = temp[10] * sdeg[w];
    float val = 0.f, m = -INFINITY;
    if (lane < 48) {
        val = hidden[(size_t)w * 48 + lane] + g * u[(size_t)w * 48 + lane];
        m = val;
    }
#pragma unroll
    for (int off = 32; off; off >>= 1) m = fmaxf(m, __shfl_xor(m, off));
    float ex = (lane < 48) ? __expf(val - m) : 0.f;
    float s = ex;
#pragma unroll
    for (int off = 32; off; off >>= 1) s += __shfl_xor(s, off);
    if (lane < 48) out[(size_t)w * 48 + lane] = val - m - __logf(s);
}

// ---------------- launch ----------------

extern "C" void kernel_launch(void* const* d_in, const int* in_sizes, int n_in,
                              void* d_out, int out_size, void* d_ws, size_t ws_size,
                              hipStream_t stream) {
    const float* x    = (const float*)d_in[0];
    const int*   ei   = (const int*)d_in[1];
    const float* W1   = (const float*)d_in[2];
    const float* b1   = (const float*)d_in[3];
    const float* W2   = (const float*)d_in[4];
    const float* b2   = (const float*)d_in[5];
    const float* temp = (const float*)d_in[6];
    float* out = (float*)d_out;

    const int N = in_sizes[0] / 256;
    const int E = in_sizes[1] / 2;
    const int* src = ei;
    const int* dst = ei + E;

    // workspace layout (4-byte units, float4-aligned)
    char* w8 = (char*)d_ws;
    size_t NP = (size_t)((N + 63) & ~63);
    int*   cnt     = (int*)w8;                        // N
    int*   rowptr  = cnt + NP;                        // N
    int*   cursor  = rowptr + NP;                     // N
    int*   blk     = cursor + NP;                     // 256
    float* dinv    = (float*)(blk + 256);             // N
    float* dinv2   = dinv + NP;                       // N
    float* sdeg    = dinv2 + NP;                      // N
    int*   csr_src = (int*)(sdeg + NP);               // E
    float* h       = (float*)(csr_src + ((E + 15) & ~15)); // N*48 (u0)
    float* bufB    = h + (size_t)N * 48;              // N*48
    float* hidden  = bufB + (size_t)N * 48;           // N*48
    float* h1      = hidden + (size_t)N * 48;         // N*256 (dead after gemm2)
    float* bufA    = h1;                              // aliases h1

    const int nb = (N + 255) / 256;                   // 196 <= 256

    // CSR build
    k_zero <<<(N + 255) / 256, 256, 0, stream>>>(cnt, N);
    k_count<<<(E + 255) / 256, 256, 0, stream>>>(dst, cnt, E);
    k_dinv <<<(N + 255) / 256, 256, 0, stream>>>(cnt, dinv, dinv2, sdeg, N);
    k_scan1<<<nb, 256, 0, stream>>>(cnt, rowptr, blk, N);
    k_scan2<<<1, 256, 0, stream>>>(blk, nb);
    k_scan3<<<nb, 256, 0, stream>>>(rowptr, cursor, blk, N);
    k_fill <<<(E + 255) / 256, 256, 0, stream>>>(src, dst, cursor, csr_src, E);

    // MLP head (gemm2 epilogue produces u0 = dinv .* h)
    dim3 g1((N + 63) / 64, 4);
    k_gemm1<<<g1, 256, 0, stream>>>(x, W1, b1, h1, N);
    k_gemm2<<<(N + 63) / 64, 256, 0, stream>>>(h1, W2, b2, dinv, h, N);

    // K-hop propagation on u-state
    const int n4 = N * 12;
    const float* cur = h;
    float* nxt = bufA;
    for (int k = 0; k < 10; ++k) {
        k_hop<<<(n4 + 255) / 256, 256, 0, stream>>>((const float4*)cur, (float4*)nxt, (float4*)hidden,
                                                    rowptr, cursor, csr_src, dinv2, sdeg, temp,
                                                    k, (k == 0) ? 1 : 0, N);
        cur = nxt;
        nxt = (nxt == bufA) ? bufB : bufA;
    }

    k_final<<<(N / 4) + 1, 256, 0, stream>>>(hidden, cur, sdeg, temp, out, N);
}